// Round 5
// baseline (1095.908 us; speedup 1.0000x reference)
//
#include <hip/hip_runtime.h>

#define B_    2
#define C_    256
#define HW_   56
#define N_    3136     // 56*56
#define NH_   8
#define D_    32
#define K1CNT 1568     // N_/2
#define K2CNT 1045     // N_//3
#define LN_EPS 1e-5f
#define SROW  3140     // padded score row; 3140%32==4
#define ROWS  4        // q-rows per block
#define PROBS 8        // ROWS * 2 top-k problems
#define NBIN  1024     // w-space bins: 8 exponents x 128 mantissa slots
#define WBASE 14336    // (127-15)<<7 ; covers w=exp(s-8) for s in (-2.40, 3.15)
#define HISTW 2048     // ROWS * 512 u32 words (u16-packed bin pairs)
#define CAP   256      // candidate capacity per problem (~25 expected per bin)
#define RM    8.0f     // row-uniform exp shift (softmax shift-invariant; |s| << 8)

typedef float f32x2 __attribute__((ext_vector_type(2)));
#define PKFMA(a, b, c) __builtin_elementwise_fma(a, b, c)   // -> v_pk_fma_f32

// LDS: S 50240 | X 8192 (hist -> cand -> red, disjoint lifetimes) | misc
// total ~58.7 KB  ->  2 blocks/CU (32 waves = CU wave cap)

// full-wave sum: xor-butterfly via ds_swizzle + cross-32 shfl
__device__ inline float redsum64(float v) {
    v += __int_as_float(__builtin_amdgcn_ds_swizzle(__float_as_int(v), 0x041F)); // xor 1
    v += __int_as_float(__builtin_amdgcn_ds_swizzle(__float_as_int(v), 0x081F)); // xor 2
    v += __int_as_float(__builtin_amdgcn_ds_swizzle(__float_as_int(v), 0x101F)); // xor 4
    v += __int_as_float(__builtin_amdgcn_ds_swizzle(__float_as_int(v), 0x201F)); // xor 8
    v += __int_as_float(__builtin_amdgcn_ds_swizzle(__float_as_int(v), 0x401F)); // xor 16
    v += __shfl_xor(v, 32, 64);
    return v;
}

// sum over jj4 groups (xor 8,16,32)
__device__ inline float avred(float v) {
    v += __int_as_float(__builtin_amdgcn_ds_swizzle(__float_as_int(v), 0x201F)); // xor 8
    v += __int_as_float(__builtin_amdgcn_ds_swizzle(__float_as_int(v), 0x401F)); // xor 16
    v += __shfl_xor(v, 32, 64);
    return v;
}

// ---------------- pooling (3 avg pools summed, zero-pad, divisor k*k) -------
__global__ void pool_kernel(const float* __restrict__ y, float* __restrict__ yp)
{
    int gid = blockIdx.x * 256 + threadIdx.x;
    int n  = gid % N_;
    int bc = gid / N_;
    const float* src = y + (size_t)bc * N_;
    int x0 = n % HW_, y0 = n / HW_;
    float acc = 0.f;
#pragma unroll
    for (int dy = -3; dy <= 3; ++dy) {
        int yy = y0 + dy;
        if ((unsigned)yy >= HW_) continue;
#pragma unroll
        for (int dx = -3; dx <= 3; ++dx) {
            int xx = x0 + dx;
            if ((unsigned)xx >= HW_) continue;
            float w = 1.f / 49.f;
            if (dy >= -2 && dy <= 2 && dx >= -2 && dx <= 2) w += 1.f / 25.f;
            if (dy >= -1 && dy <= 1 && dx >= -1 && dx <= 1) w += 1.f / 9.f;
            acc += w * src[yy * HW_ + xx];
        }
    }
    yp[gid] = acc;
}

// ---------------- layernorm over C, writes transposed [B,C,N] ---------------
__global__ void ln_kernel(const float* __restrict__ yp, const float* __restrict__ lnw,
                          const float* __restrict__ lnb, float* __restrict__ yfT)
{
    __shared__ float wr[8];
    __shared__ float stats[2];
    int idx = blockIdx.x;
    int b = idx / N_, n = idx % N_;
    int c = threadIdx.x;
    size_t off = ((size_t)b * C_ + c) * N_ + n;
    float v = yp[off];
    float s = v, q = v * v;
    int lane = threadIdx.x & 63, wid = threadIdx.x >> 6;
#pragma unroll
    for (int d = 32; d; d >>= 1) { s += __shfl_down(s, d, 64); q += __shfl_down(q, d, 64); }
    if (lane == 0) { wr[wid] = s; wr[4 + wid] = q; }
    __syncthreads();
    if (threadIdx.x == 0) {
        float ts = wr[0] + wr[1] + wr[2] + wr[3];
        float tq = wr[4] + wr[5] + wr[6] + wr[7];
        float mu = ts * (1.f / C_);
        float var = tq * (1.f / C_) - mu * mu;
        stats[0] = mu; stats[1] = rsqrtf(var + LN_EPS);
    }
    __syncthreads();
    yfT[off] = (v - stats[0]) * stats[1] * lnw[c] + lnb[c];
}

// ---------------- GEMM: out = A(AT layout [B,C,N]) @ W[O,K]^T + bias --------
__global__ __launch_bounds__(256) void gemm_qkv(
    const float* __restrict__ A, const float* __restrict__ W,
    const float* __restrict__ bias, float* __restrict__ dst0,
    float* __restrict__ dst1, float scale)
{
    __shared__ float As[16][64];
    __shared__ float Ws[16][68];
    int tid = threadIdx.x;
    int m0 = blockIdx.x * 64;
    int b = m0 / N_, n0 = m0 % N_;
    int o0 = blockIdx.y * 64;
    const float* Ab = A + (size_t)b * C_ * N_;
    f32x2 accP[2][4] = {};       // [o-pair][m], o packed in f32x2 lanes
    int la_k = tid >> 4;
    int la_m = (tid & 15) * 4;
    int lw_o = tid >> 2;
    int lw_k = (tid & 3) * 4;
    int u  = tid & 15;
    int v_ = tid >> 4;
    for (int kt = 0; kt < 16; ++kt) {
        int k0 = kt * 16;
        float4 av = *(const float4*)&Ab[(size_t)(k0 + la_k) * N_ + n0 + la_m];
        float4 wv = *(const float4*)&W[(size_t)(o0 + lw_o) * C_ + k0 + lw_k];
        __syncthreads();
        *(float4*)&As[la_k][la_m] = av;
        Ws[lw_k + 0][lw_o] = wv.x; Ws[lw_k + 1][lw_o] = wv.y;
        Ws[lw_k + 2][lw_o] = wv.z; Ws[lw_k + 3][lw_o] = wv.w;
        __syncthreads();
#pragma unroll
        for (int k = 0; k < 16; ++k) {
            float4 wf = *(const float4*)&Ws[k][u * 4];
            f32x2 wlo = { wf.x, wf.y }, whi = { wf.z, wf.w };
            float a0 = As[k][v_], a1 = As[k][v_ + 16], a2 = As[k][v_ + 32], a3 = As[k][v_ + 48];
            f32x2 s0 = { a0, a0 }, s1 = { a1, a1 }, s2 = { a2, a2 }, s3 = { a3, a3 };
            accP[0][0] = PKFMA(wlo, s0, accP[0][0]); accP[1][0] = PKFMA(whi, s0, accP[1][0]);
            accP[0][1] = PKFMA(wlo, s1, accP[0][1]); accP[1][1] = PKFMA(whi, s1, accP[1][1]);
            accP[0][2] = PKFMA(wlo, s2, accP[0][2]); accP[1][2] = PKFMA(whi, s2, accP[1][2]);
            accP[0][3] = PKFMA(wlo, s3, accP[0][3]); accP[1][3] = PKFMA(whi, s3, accP[1][3]);
        }
    }
    int oc = o0 + u * 4;
    float b0v = bias[oc], b1v = bias[oc + 1], b2v = bias[oc + 2], b3v = bias[oc + 3];
    float* dst = dst0; int c2 = oc;
    if (dst1 && oc >= C_) { dst = dst1; c2 = oc - C_; }
    int h = c2 >> 5, d0 = c2 & 31;
    size_t base = ((size_t)b * NH_ + h) * N_ * D_;
#pragma unroll
    for (int j = 0; j < 4; ++j) {
        int n = n0 + v_ + j * 16;
        float4 val;
        val.x = (accP[0][j].x + b0v) * scale;
        val.y = (accP[0][j].y + b1v) * scale;
        val.z = (accP[1][j].x + b2v) * scale;
        val.w = (accP[1][j].y + b3v) * scale;
        *(float4*)&dst[base + (size_t)n * D_ + d0] = val;
    }
}

__global__ __launch_bounds__(256) void gemm_proj(
    const float* __restrict__ A, const float* __restrict__ W,
    const float* __restrict__ bias, float* __restrict__ out)
{
    __shared__ float As[16][64];
    __shared__ float Ws[16][68];
    int tid = threadIdx.x;
    int m0 = blockIdx.x * 64;
    int b = m0 / N_, n0 = m0 % N_;
    int o0 = blockIdx.y * 64;
    const float* Ab = A + (size_t)b * C_ * N_;
    f32x2 accP[4][2] = {};       // [o][j-pair], j packed in f32x2 lanes
    int la_k = tid >> 4;
    int la_m = (tid & 15) * 4;
    int lw_o = tid >> 2;
    int lw_k = (tid & 3) * 4;
    int u  = tid & 15;
    int v_ = tid >> 4;
    for (int kt = 0; kt < 16; ++kt) {
        int k0 = kt * 16;
        float4 av = *(const float4*)&Ab[(size_t)(k0 + la_k) * N_ + n0 + la_m];
        float4 wv = *(const float4*)&W[(size_t)(o0 + lw_o) * C_ + k0 + lw_k];
        __syncthreads();
        *(float4*)&As[la_k][la_m] = av;
        Ws[lw_k + 0][lw_o] = wv.x; Ws[lw_k + 1][lw_o] = wv.y;
        Ws[lw_k + 2][lw_o] = wv.z; Ws[lw_k + 3][lw_o] = wv.w;
        __syncthreads();
#pragma unroll
        for (int k = 0; k < 16; ++k) {
            float4 af = *(const float4*)&As[k][u * 4];
            f32x2 alo = { af.x, af.y }, ahi = { af.z, af.w };
            float w0 = Ws[k][v_], w1 = Ws[k][v_ + 16], w2 = Ws[k][v_ + 32], w3 = Ws[k][v_ + 48];
            f32x2 p0 = { w0, w0 }, p1 = { w1, w1 }, p2 = { w2, w2 }, p3 = { w3, w3 };
            accP[0][0] = PKFMA(p0, alo, accP[0][0]); accP[0][1] = PKFMA(p0, ahi, accP[0][1]);
            accP[1][0] = PKFMA(p1, alo, accP[1][0]); accP[1][1] = PKFMA(p1, ahi, accP[1][1]);
            accP[2][0] = PKFMA(p2, alo, accP[2][0]); accP[2][1] = PKFMA(p2, ahi, accP[2][1]);
            accP[3][0] = PKFMA(p3, alo, accP[3][0]); accP[3][1] = PKFMA(p3, ahi, accP[3][1]);
        }
    }
#pragma unroll
    for (int i = 0; i < 4; ++i) {
        int o = o0 + v_ + i * 16;
        float bb = bias[o];
        float4 val;
        val.x = accP[i][0].x + bb; val.y = accP[i][0].y + bb;
        val.z = accP[i][1].x + bb; val.w = accP[i][1].y + bb;
        *(float4*)&out[((size_t)b * C_ + o) * N_ + n0 + u * 4] = val;
    }
}

// ---------------- fused attention (1024 threads, 16 waves, 4 q-rows) --------
// w-space selection: S holds w = exp(s - RM) > 0; float order == unsigned bit
// order, so all thresholds are plain u32 compares and no exp/ordf downstream.
struct AttnMisc {
    unsigned thrBin[PROBS];
    int selrM[PROBS];
    unsigned thrU[PROBS];
    unsigned cntM[PROBS];
    float coef[PROBS];
    float pp[2];
    float wred[32];      // 16 waves x {dsum1, dsum2} of its row
};

// radix refine over low 16 bits + boundary sum of candidate w's (in regs)
#define REFINE_BSUM(NV)                                                    \
    {                                                                      \
        unsigned vv[NV]; unsigned aok = 0;                                 \
        _Pragma("unroll")                                                  \
        for (int t = 0; t < NV; ++t) {                                     \
            int idx = lane + (t << 6);                                     \
            bool ok = idx < cnt;                                           \
            vv[t] = ok ? cp[idx] : 0u;                                     \
            if (ok) aok |= 1u << t;                                        \
        }                                                                  \
        unsigned act = aok;                                                \
        for (int b = 15; b >= 0; --b) {                                    \
            unsigned msk = 0, c = 0;                                       \
            _Pragma("unroll")                                              \
            for (int t = 0; t < NV; ++t) {                                 \
                bool p = ((act >> t) & 1u) && ((vv[t] >> b) & 1u);         \
                c += (unsigned)__popcll(__ballot(p));                      \
                if (p) msk |= 1u << t;                                     \
            }                                                              \
            if (c >= kk) { act = msk; bits |= 1u << b; }                   \
            else { kk -= c; act &= ~msk; }                                 \
        }                                                                  \
        unsigned thr = lo | bits;                                          \
        _Pragma("unroll")                                                  \
        for (int t = 0; t < NV; ++t) {                                     \
            if (((aok >> t) & 1u) && vv[t] >= thr)                         \
                bsum += __uint_as_float(vv[t]);                            \
        }                                                                  \
    }

__global__ __launch_bounds__(1024, 8) void attn_kernel(
    const float* __restrict__ qh, const float* __restrict__ kh, const float* __restrict__ vh,
    const float* __restrict__ p1p, const float* __restrict__ p2p,
    float* __restrict__ aoT)
{
    extern __shared__ char smem[];
    float*    S    = (float*)smem;                    // 4*3140 f32 = 50240 B
    unsigned* hist = (unsigned*)(smem + 50240);       // 4*512 u32 (u16-packed)
    unsigned* cand = (unsigned*)(smem + 50240);       // 8*256 u32 (after search)
    float*    red  = (float*)(smem + 50240);          // 16*128 f32 (AV epilogue)
    AttnMisc* M    = (AttnMisc*)(smem + 50240 + 8192);

    int tid = threadIdx.x, lane = tid & 63, wid = tid >> 6;
    int bh = blockIdx.y, n0 = blockIdx.x * ROWS;
    size_t bhN = (size_t)bh * N_;

    if (tid < PROBS) M->cntM[tid] = 0u;
    if (tid == 0) { M->pp[0] = p1p[0]; M->pp[1] = p2p[0]; }
    if (tid < HISTW) hist[tid] = 0u;
    if (tid + 1024 < HISTW) hist[tid + 1024] = 0u;
    __syncthreads();

    // ---- P0: w = exp(s-RM) + fine w-space histogram (packed fp32 QK dot) ----
    const float* qrow = qh + (bhN + n0) * D_;
    for (int i = 0; i < 4; ++i) {
        int j = tid + (i << 10);
        if (j < N_) {
            const float4* kp = (const float4*)(kh + (bhN + j) * D_);
            float4 k4[8];
#pragma unroll
            for (int q = 0; q < 8; ++q) k4[q] = kp[q];
#pragma unroll
            for (int r = 0; r < ROWS; ++r) {
                const float4* qp = (const float4*)(qrow + r * D_);
                f32x2 aA = { 0.f, 0.f }, aB = { 0.f, 0.f };
#pragma unroll
                for (int q = 0; q < 8; ++q) {
                    float4 q4 = qp[q];
                    f32x2 ql = { q4.x, q4.y }, qh2 = { q4.z, q4.w };
                    f32x2 kl = { k4[q].x, k4[q].y }, kh2 = { k4[q].z, k4[q].w };
                    aA = PKFMA(ql, kl, aA);
                    aB = PKFMA(qh2, kh2, aB);
                }
                float s = (aA.x + aA.y) + (aB.x + aB.y);
                float w = __expf(s - RM);
                S[r * SROW + j] = w;
                int bin = (int)(__float_as_uint(w) >> 16) - WBASE;
                bin = max(0, min(bin, NBIN - 1));
                atomicAdd(&hist[(r << 9) + (bin >> 1)], 1u << ((bin & 1) << 4));
            }
        }
    }
    __syncthreads();

    // ---- histogram search (wave w -> problem w, w<8): 16 bins per lane ----
    if (wid < PROBS) {
        int prob = wid;
        int r = prob >> 1;
        int k = (prob & 1) ? K2CNT : K1CNT;
        const unsigned* hrow = hist + (r << 9) + (lane << 3);
        uint4 ha = *(const uint4*)(hrow + 0);
        uint4 hb = *(const uint4*)(hrow + 4);
        unsigned hh[8] = { ha.x, ha.y, ha.z, ha.w, hb.x, hb.y, hb.z, hb.w };
        unsigned usum = 0;
#pragma unroll
        for (int t = 0; t < 8; ++t) usum += hh[t];
        int ltot = (int)((usum & 0xFFFFu) + (usum >> 16));   // row total <= 3136: no carry
        int s = ltot;
#pragma unroll
        for (int d = 1; d < 64; d <<= 1) {
            int o = __shfl_down(s, d, 64);
            if (lane + d < 64) s += o;
        }
        int after = s - ltot;            // counts in higher lanes' (larger) bins
        if (after < k && after + ltot >= k) {   // crossing lane (unique)
            int g = after, b0 = -1, selr = 0;
#pragma unroll
            for (int m = 15; m >= 0; --m) {
                unsigned w = hh[m >> 1];
                int cm = (m & 1) ? (int)(w >> 16) : (int)(w & 0xFFFFu);
                g += cm;
                if (b0 < 0 && g >= k) { b0 = (lane << 4) + m; selr = k - (g - cm); }
            }
            M->thrBin[prob] = (unsigned)b0;
            M->selrM[prob] = selr;
        }
    }
    __syncthreads();

    // ---- P1: gather candidates + definite exp-sums (row-per-wave-group) ----
    {
        int row = wid >> 2;
        int sub = ((wid & 3) << 6) | lane;      // 0..255 within row group
        unsigned lo1 = (unsigned)(WBASE + M->thrBin[2 * row]) << 16, hi1 = lo1 + 0x10000u;
        unsigned lo2 = (unsigned)(WBASE + M->thrBin[2 * row + 1]) << 16, hi2 = lo2 + 0x10000u;
        int p1 = 2 * row, p2 = 2 * row + 1;
        float ds1 = 0.f, ds2 = 0.f;
        const float* Srow = S + row * SROW;
#pragma unroll
        for (int i = 0; i < 4; ++i) {
            int q = sub + (i << 8);
            if (q < 784) {                       // 784 quads * 4 = 3136
                float4 sv = *(const float4*)&Srow[q << 2];
                float sa[4] = { sv.x, sv.y, sv.z, sv.w };
#pragma unroll
                for (int t = 0; t < 4; ++t) {
                    unsigned u = __float_as_uint(sa[t]);
                    if (u >= hi1) {
                        ds1 += sa[t];
                        if (u >= hi2) ds2 += sa[t];
                    } else if (u >= lo1) {
                        unsigned ix = atomicAdd(&M->cntM[p1], 1u);
                        if (ix < CAP) cand[p1 * CAP + ix] = u;
                    }
                    if (u >= lo2 && u < hi2) {
                        unsigned ix = atomicAdd(&M->cntM[p2], 1u);
                        if (ix < CAP) cand[p2 * CAP + ix] = u;
                    }
                }
            }
        }
        ds1 = redsum64(ds1);
        ds2 = redsum64(ds2);
        if (lane == 0) { M->wred[wid * 2] = ds1; M->wred[wid * 2 + 1] = ds2; }
    }
    __syncthreads();

    // ---- refine (16-bit ballot-radix) + boundary sums + coef ----
    if (wid < PROBS) {
        int prob = wid;
        int cnt = (int)M->cntM[prob]; if (cnt > CAP) cnt = CAP;
        unsigned kk = (unsigned)M->selrM[prob];
        unsigned lo = (unsigned)(WBASE + M->thrBin[prob]) << 16;
        const unsigned* cp = cand + prob * CAP;
        unsigned bits = 0;
        float bsum = 0.f;
        if (cnt <= 64)       REFINE_BSUM(1)
        else if (cnt <= 128) REFINE_BSUM(2)
        else                 REFINE_BSUM(4)
        bsum = redsum64(bsum);
        if (lane == 0) {
            M->thrU[prob] = lo | bits;
            int rw = (prob >> 1) << 2;           // first wave of this row's group
            float denom = bsum
                + M->wred[(rw + 0) * 2 + (prob & 1)]
                + M->wred[(rw + 1) * 2 + (prob & 1)]
                + M->wred[(rw + 2) * 2 + (prob & 1)]
                + M->wred[(rw + 3) * 2 + (prob & 1)];
            M->coef[prob] = M->pp[prob & 1] / denom;
        }
    }
    __syncthreads();

    // ---- transform: w -> final AV coefficient (no exp, no ordf) ----
    {
        int row = wid >> 2;
        int sub = ((wid & 3) << 6) | lane;
        unsigned u1 = M->thrU[2 * row], u2 = M->thrU[2 * row + 1];
        float c1 = M->coef[2 * row];
        float c12 = c1 + M->coef[2 * row + 1];
        float* Srow = S + row * SROW;
#pragma unroll
        for (int i = 0; i < 4; ++i) {
            int q = sub + (i << 8);
            if (q < 784) {
                float4 sv = *(const float4*)&Srow[q << 2];
                float sa[4] = { sv.x, sv.y, sv.z, sv.w };
#pragma unroll
                for (int t = 0; t < 4; ++t) {
                    unsigned u = __float_as_uint(sa[t]);
                    float sel = (u >= u2) ? c12 : c1;
                    sa[t] = (u >= u1) ? sa[t] * sel : 0.f;
                }
                *(float4*)&Srow[q << 2] = make_float4(sa[0], sa[1], sa[2], sa[3]);
            }
        }
    }
    __syncthreads();

    // ---- AV: 32-j groups, V direct from global, packed fp32 accumulate ----
    int jj4 = lane >> 3, dq = lane & 7;
    f32x2 accL[ROWS], accH[ROWS];
#pragma unroll
    for (int r = 0; r < ROWS; ++r) { accL[r] = (f32x2){0.f, 0.f}; accH[r] = (f32x2){0.f, 0.f}; }
    const float* vbase = vh + bhN * D_ + (dq << 2);
    for (int g = wid; g < 98; g += 16) {        // 98 groups of 32 j
        int jb = (g << 5) + (jj4 << 2);
        float4 v0 = *(const float4*)(vbase + (size_t)(jb + 0) * D_);
        float4 v1 = *(const float4*)(vbase + (size_t)(jb + 1) * D_);
        float4 v2 = *(const float4*)(vbase + (size_t)(jb + 2) * D_);
        float4 v3 = *(const float4*)(vbase + (size_t)(jb + 3) * D_);
        f32x2 v0l = { v0.x, v0.y }, v0h = { v0.z, v0.w };
        f32x2 v1l = { v1.x, v1.y }, v1h = { v1.z, v1.w };
        f32x2 v2l = { v2.x, v2.y }, v2h = { v2.z, v2.w };
        f32x2 v3l = { v3.x, v3.y }, v3h = { v3.z, v3.w };
#pragma unroll
        for (int r = 0; r < ROWS; ++r) {
            float4 s4 = *(const float4*)&S[r * SROW + jb];
            f32x2 c0 = { s4.x, s4.x }, c1 = { s4.y, s4.y };
            f32x2 c2 = { s4.z, s4.z }, c3 = { s4.w, s4.w };
            accL[r] = PKFMA(c0, v0l, accL[r]); accH[r] = PKFMA(c0, v0h, accH[r]);
            accL[r] = PKFMA(c1, v1l, accL[r]); accH[r] = PKFMA(c1, v1h, accH[r]);
            accL[r] = PKFMA(c2, v2l, accL[r]); accH[r] = PKFMA(c2, v2h, accH[r]);
            accL[r] = PKFMA(c3, v3l, accL[r]); accH[r] = PKFMA(c3, v3h, accH[r]);
        }
    }
#pragma unroll
    for (int r = 0; r < ROWS; ++r) {
        float rx = avred(accL[r].x);
        float ry = avred(accL[r].y);
        float rz = avred(accH[r].x);
        float rw = avred(accH[r].y);
        if (lane < 8)
            *(float4*)&red[(wid << 7) + (r << 5) + (lane << 2)] = make_float4(rx, ry, rz, rw);
    }
    __syncthreads();
    if (tid < 32 * ROWS) {
        float o = 0.f;
#pragma unroll
        for (int w = 0; w < 16; ++w) o += red[(w << 7) + tid];
        int r = tid >> 5, d = tid & 31;
        int b = bh >> 3, h = bh & 7;
        aoT[((size_t)(b * C_ + h * 32 + d)) * N_ + n0 + r] = o;
    }
}

static const int ATTN_SMEM = 50240 + 8192 + (int)sizeof(AttnMisc);

extern "C" void kernel_launch(void* const* d_in, const int* in_sizes, int n_in,
                              void* d_out, int out_size, void* d_ws, size_t ws_size,
                              hipStream_t stream)
{
    (void)in_sizes; (void)n_in; (void)out_size; (void)ws_size;
    const float* x    = (const float*)d_in[0];
    const float* y    = (const float*)d_in[1];
    const float* q_w  = (const float*)d_in[2];
    const float* q_b  = (const float*)d_in[3];
    const float* kv_w = (const float*)d_in[4];
    const float* kv_b = (const float*)d_in[5];
    const float* p_w  = (const float*)d_in[6];
    const float* p_b  = (const float*)d_in[7];
    const float* lnw  = (const float*)d_in[8];
    const float* lnb  = (const float*)d_in[9];
    const float* a1p  = (const float*)d_in[10];
    const float* a2p  = (const float*)d_in[11];
    float* out = (float*)d_out;

    float* ws = (float*)d_ws;
    const size_t PLANE = (size_t)B_ * C_ * N_;
    float* yp  = ws;
    float* yfT = ws + PLANE;
    float* qh_ = ws + 2 * PLANE;
    float* kh_ = ws + 3 * PLANE;
    float* vh_ = ws + 4 * PLANE;
    float* aoT = ws + 5 * PLANE;

    pool_kernel<<<dim3((unsigned)(PLANE / 256)), 256, 0, stream>>>(y, yp);
    ln_kernel<<<dim3(B_ * N_), 256, 0, stream>>>(yp, lnw, lnb, yfT);
    gemm_qkv<<<dim3(98, 4), 256, 0, stream>>>(x, q_w, q_b, qh_, nullptr, 0.17677669529663687f);
    gemm_qkv<<<dim3(98, 8), 256, 0, stream>>>(yfT, kv_w, kv_b, kh_, vh_, 1.0f);
    hipFuncSetAttribute(reinterpret_cast<const void*>(attn_kernel),
                        hipFuncAttributeMaxDynamicSharedMemorySize, ATTN_SMEM);
    attn_kernel<<<dim3(N_ / ROWS, B_ * NH_), 1024, ATTN_SMEM, stream>>>(qh_, kh_, vh_, a1p, a2p, aoT);
    gemm_proj<<<dim3(98, 4), 256, 0, stream>>>(aoT, p_w, p_b, out);
}

// Round 6
// 941.620 us; speedup vs baseline: 1.1639x; 1.1639x over previous
//
#include <hip/hip_runtime.h>

#define B_    2
#define C_    256
#define HW_   56
#define N_    3136     // 56*56
#define NH_   8
#define D_    32
#define K1CNT 1568     // N_/2
#define K2CNT 1045     // N_//3
#define LN_EPS 1e-5f
#define SROW  3140     // padded score row; 3140%32==4
#define ROWS  4        // q-rows per block
#define PROBS 8        // ROWS * 2 top-k problems
#define NBIN  1024     // w-space bins: 8 exponents x 128 mantissa slots
#define WBASE 14336    // (127-15)<<7 ; covers w=exp(s-8) for s in (-2.40, 3.15)
#define HISTW 2048     // ROWS * 512 u32 words (u16-packed bin pairs)
#define CAP   256      // candidate capacity per problem (~25 expected per bin)
#define RM    8.0f     // row-uniform exp shift (softmax shift-invariant; |s| << 8)

typedef float f32x2 __attribute__((ext_vector_type(2)));
#define PKFMA(a, b, c) __builtin_elementwise_fma(a, b, c)   // -> v_pk_fma_f32

// NOTE (R4 post-mortem): pk_fma in attn_kernel spilled under the
// __launch_bounds__(1024,8) VGPR cap (WRITE_SIZE 12.5->177 MB, +185 us).
// attn stays scalar-FMA; GEMMs (256-thr, no cap pressure) keep pk_fma.

// full-wave sum: xor-butterfly via ds_swizzle + cross-32 shfl
__device__ inline float redsum64(float v) {
    v += __int_as_float(__builtin_amdgcn_ds_swizzle(__float_as_int(v), 0x041F)); // xor 1
    v += __int_as_float(__builtin_amdgcn_ds_swizzle(__float_as_int(v), 0x081F)); // xor 2
    v += __int_as_float(__builtin_amdgcn_ds_swizzle(__float_as_int(v), 0x101F)); // xor 4
    v += __int_as_float(__builtin_amdgcn_ds_swizzle(__float_as_int(v), 0x201F)); // xor 8
    v += __int_as_float(__builtin_amdgcn_ds_swizzle(__float_as_int(v), 0x401F)); // xor 16
    v += __shfl_xor(v, 32, 64);
    return v;
}

// sum over jj4 groups (xor 8,16,32)
__device__ inline float avred(float v) {
    v += __int_as_float(__builtin_amdgcn_ds_swizzle(__float_as_int(v), 0x201F)); // xor 8
    v += __int_as_float(__builtin_amdgcn_ds_swizzle(__float_as_int(v), 0x401F)); // xor 16
    v += __shfl_xor(v, 32, 64);
    return v;
}

// ---------------- pooling (3 avg pools summed, zero-pad, divisor k*k) -------
__global__ void pool_kernel(const float* __restrict__ y, float* __restrict__ yp)
{
    int gid = blockIdx.x * 256 + threadIdx.x;
    int n  = gid % N_;
    int bc = gid / N_;
    const float* src = y + (size_t)bc * N_;
    int x0 = n % HW_, y0 = n / HW_;
    float acc = 0.f;
#pragma unroll
    for (int dy = -3; dy <= 3; ++dy) {
        int yy = y0 + dy;
        if ((unsigned)yy >= HW_) continue;
#pragma unroll
        for (int dx = -3; dx <= 3; ++dx) {
            int xx = x0 + dx;
            if ((unsigned)xx >= HW_) continue;
            float w = 1.f / 49.f;
            if (dy >= -2 && dy <= 2 && dx >= -2 && dx <= 2) w += 1.f / 25.f;
            if (dy >= -1 && dy <= 1 && dx >= -1 && dx <= 1) w += 1.f / 9.f;
            acc += w * src[yy * HW_ + xx];
        }
    }
    yp[gid] = acc;
}

// ---------------- layernorm over C, writes transposed [B,C,N] ---------------
__global__ void ln_kernel(const float* __restrict__ yp, const float* __restrict__ lnw,
                          const float* __restrict__ lnb, float* __restrict__ yfT)
{
    __shared__ float wr[8];
    __shared__ float stats[2];
    int idx = blockIdx.x;
    int b = idx / N_, n = idx % N_;
    int c = threadIdx.x;
    size_t off = ((size_t)b * C_ + c) * N_ + n;
    float v = yp[off];
    float s = v, q = v * v;
    int lane = threadIdx.x & 63, wid = threadIdx.x >> 6;
#pragma unroll
    for (int d = 32; d; d >>= 1) { s += __shfl_down(s, d, 64); q += __shfl_down(q, d, 64); }
    if (lane == 0) { wr[wid] = s; wr[4 + wid] = q; }
    __syncthreads();
    if (threadIdx.x == 0) {
        float ts = wr[0] + wr[1] + wr[2] + wr[3];
        float tq = wr[4] + wr[5] + wr[6] + wr[7];
        float mu = ts * (1.f / C_);
        float var = tq * (1.f / C_) - mu * mu;
        stats[0] = mu; stats[1] = rsqrtf(var + LN_EPS);
    }
    __syncthreads();
    yfT[off] = (v - stats[0]) * stats[1] * lnw[c] + lnb[c];
}

// ---------------- GEMM: out = A(AT layout [B,C,N]) @ W[O,K]^T + bias --------
__global__ __launch_bounds__(256) void gemm_qkv(
    const float* __restrict__ A, const float* __restrict__ W,
    const float* __restrict__ bias, float* __restrict__ dst0,
    float* __restrict__ dst1, float scale)
{
    __shared__ float As[16][64];
    __shared__ float Ws[16][68];
    int tid = threadIdx.x;
    int m0 = blockIdx.x * 64;
    int b = m0 / N_, n0 = m0 % N_;
    int o0 = blockIdx.y * 64;
    const float* Ab = A + (size_t)b * C_ * N_;
    f32x2 accP[2][4] = {};       // [o-pair][m], o packed in f32x2 lanes
    int la_k = tid >> 4;
    int la_m = (tid & 15) * 4;
    int lw_o = tid >> 2;
    int lw_k = (tid & 3) * 4;
    int u  = tid & 15;
    int v_ = tid >> 4;
    for (int kt = 0; kt < 16; ++kt) {
        int k0 = kt * 16;
        float4 av = *(const float4*)&Ab[(size_t)(k0 + la_k) * N_ + n0 + la_m];
        float4 wv = *(const float4*)&W[(size_t)(o0 + lw_o) * C_ + k0 + lw_k];
        __syncthreads();
        *(float4*)&As[la_k][la_m] = av;
        Ws[lw_k + 0][lw_o] = wv.x; Ws[lw_k + 1][lw_o] = wv.y;
        Ws[lw_k + 2][lw_o] = wv.z; Ws[lw_k + 3][lw_o] = wv.w;
        __syncthreads();
#pragma unroll
        for (int k = 0; k < 16; ++k) {
            float4 wf = *(const float4*)&Ws[k][u * 4];
            f32x2 wlo = { wf.x, wf.y }, whi = { wf.z, wf.w };
            float a0 = As[k][v_], a1 = As[k][v_ + 16], a2 = As[k][v_ + 32], a3 = As[k][v_ + 48];
            f32x2 s0 = { a0, a0 }, s1 = { a1, a1 }, s2 = { a2, a2 }, s3 = { a3, a3 };
            accP[0][0] = PKFMA(wlo, s0, accP[0][0]); accP[1][0] = PKFMA(whi, s0, accP[1][0]);
            accP[0][1] = PKFMA(wlo, s1, accP[0][1]); accP[1][1] = PKFMA(whi, s1, accP[1][1]);
            accP[0][2] = PKFMA(wlo, s2, accP[0][2]); accP[1][2] = PKFMA(whi, s2, accP[1][2]);
            accP[0][3] = PKFMA(wlo, s3, accP[0][3]); accP[1][3] = PKFMA(whi, s3, accP[1][3]);
        }
    }
    int oc = o0 + u * 4;
    float b0v = bias[oc], b1v = bias[oc + 1], b2v = bias[oc + 2], b3v = bias[oc + 3];
    float* dst = dst0; int c2 = oc;
    if (dst1 && oc >= C_) { dst = dst1; c2 = oc - C_; }
    int h = c2 >> 5, d0 = c2 & 31;
    size_t base = ((size_t)b * NH_ + h) * N_ * D_;
#pragma unroll
    for (int j = 0; j < 4; ++j) {
        int n = n0 + v_ + j * 16;
        float4 val;
        val.x = (accP[0][j].x + b0v) * scale;
        val.y = (accP[0][j].y + b1v) * scale;
        val.z = (accP[1][j].x + b2v) * scale;
        val.w = (accP[1][j].y + b3v) * scale;
        *(float4*)&dst[base + (size_t)n * D_ + d0] = val;
    }
}

__global__ __launch_bounds__(256) void gemm_proj(
    const float* __restrict__ A, const float* __restrict__ W,
    const float* __restrict__ bias, float* __restrict__ out)
{
    __shared__ float As[16][64];
    __shared__ float Ws[16][68];
    int tid = threadIdx.x;
    int m0 = blockIdx.x * 64;
    int b = m0 / N_, n0 = m0 % N_;
    int o0 = blockIdx.y * 64;
    const float* Ab = A + (size_t)b * C_ * N_;
    f32x2 accP[4][2] = {};       // [o][j-pair], j packed in f32x2 lanes
    int la_k = tid >> 4;
    int la_m = (tid & 15) * 4;
    int lw_o = tid >> 2;
    int lw_k = (tid & 3) * 4;
    int u  = tid & 15;
    int v_ = tid >> 4;
    for (int kt = 0; kt < 16; ++kt) {
        int k0 = kt * 16;
        float4 av = *(const float4*)&Ab[(size_t)(k0 + la_k) * N_ + n0 + la_m];
        float4 wv = *(const float4*)&W[(size_t)(o0 + lw_o) * C_ + k0 + lw_k];
        __syncthreads();
        *(float4*)&As[la_k][la_m] = av;
        Ws[lw_k + 0][lw_o] = wv.x; Ws[lw_k + 1][lw_o] = wv.y;
        Ws[lw_k + 2][lw_o] = wv.z; Ws[lw_k + 3][lw_o] = wv.w;
        __syncthreads();
#pragma unroll
        for (int k = 0; k < 16; ++k) {
            float4 af = *(const float4*)&As[k][u * 4];
            f32x2 alo = { af.x, af.y }, ahi = { af.z, af.w };
            float w0 = Ws[k][v_], w1 = Ws[k][v_ + 16], w2 = Ws[k][v_ + 32], w3 = Ws[k][v_ + 48];
            f32x2 p0 = { w0, w0 }, p1 = { w1, w1 }, p2 = { w2, w2 }, p3 = { w3, w3 };
            accP[0][0] = PKFMA(p0, alo, accP[0][0]); accP[0][1] = PKFMA(p0, ahi, accP[0][1]);
            accP[1][0] = PKFMA(p1, alo, accP[1][0]); accP[1][1] = PKFMA(p1, ahi, accP[1][1]);
            accP[2][0] = PKFMA(p2, alo, accP[2][0]); accP[2][1] = PKFMA(p2, ahi, accP[2][1]);
            accP[3][0] = PKFMA(p3, alo, accP[3][0]); accP[3][1] = PKFMA(p3, ahi, accP[3][1]);
        }
    }
#pragma unroll
    for (int i = 0; i < 4; ++i) {
        int o = o0 + v_ + i * 16;
        float bb = bias[o];
        float4 val;
        val.x = accP[i][0].x + bb; val.y = accP[i][0].y + bb;
        val.z = accP[i][1].x + bb; val.w = accP[i][1].y + bb;
        *(float4*)&out[((size_t)b * C_ + o) * N_ + n0 + u * 4] = val;
    }
}

// ---------------- fused attention (1024 threads, 16 waves, 4 q-rows) --------
// w-space selection: S holds w = exp(s - RM) > 0; float order == unsigned bit
// order, so all thresholds are plain u32 compares and no exp/ordf downstream.
struct AttnMisc {
    unsigned thrBin[PROBS];
    int selrM[PROBS];
    unsigned thrU[PROBS];
    unsigned cntM[PROBS];
    float coef[PROBS];
    float pp[2];
    float wred[32];      // 16 waves x {dsum1, dsum2} of its row
};

// radix refine over low 16 bits + boundary sum of candidate w's (in regs)
#define REFINE_BSUM(NV)                                                    \
    {                                                                      \
        unsigned vv[NV]; unsigned aok = 0;                                 \
        _Pragma("unroll")                                                  \
        for (int t = 0; t < NV; ++t) {                                     \
            int idx = lane + (t << 6);                                     \
            bool ok = idx < cnt;                                           \
            vv[t] = ok ? cp[idx] : 0u;                                     \
            if (ok) aok |= 1u << t;                                        \
        }                                                                  \
        unsigned act = aok;                                                \
        for (int b = 15; b >= 0; --b) {                                    \
            unsigned msk = 0, c = 0;                                       \
            _Pragma("unroll")                                              \
            for (int t = 0; t < NV; ++t) {                                 \
                bool p = ((act >> t) & 1u) && ((vv[t] >> b) & 1u);         \
                c += (unsigned)__popcll(__ballot(p));                      \
                if (p) msk |= 1u << t;                                     \
            }                                                              \
            if (c >= kk) { act = msk; bits |= 1u << b; }                   \
            else { kk -= c; act &= ~msk; }                                 \
        }                                                                  \
        unsigned thr = lo | bits;                                          \
        _Pragma("unroll")                                                  \
        for (int t = 0; t < NV; ++t) {                                     \
            if (((aok >> t) & 1u) && vv[t] >= thr)                         \
                bsum += __uint_as_float(vv[t]);                            \
        }                                                                  \
    }

__global__ __launch_bounds__(1024, 8) void attn_kernel(
    const float* __restrict__ qh, const float* __restrict__ kh, const float* __restrict__ vh,
    const float* __restrict__ p1p, const float* __restrict__ p2p,
    float* __restrict__ aoT)
{
    extern __shared__ char smem[];
    float*    S    = (float*)smem;                    // 4*3140 f32 = 50240 B
    unsigned* hist = (unsigned*)(smem + 50240);       // 4*512 u32 (u16-packed)
    unsigned* cand = (unsigned*)(smem + 50240);       // 8*256 u32 (after search)
    float*    red  = (float*)(smem + 50240);          // 16*128 f32 (AV epilogue)
    AttnMisc* M    = (AttnMisc*)(smem + 50240 + 8192);

    int tid = threadIdx.x, lane = tid & 63, wid = tid >> 6;
    int bh = blockIdx.y, n0 = blockIdx.x * ROWS;
    size_t bhN = (size_t)bh * N_;

    if (tid < PROBS) M->cntM[tid] = 0u;
    if (tid == 0) { M->pp[0] = p1p[0]; M->pp[1] = p2p[0]; }
    if (tid < HISTW) hist[tid] = 0u;
    if (tid + 1024 < HISTW) hist[tid + 1024] = 0u;
    __syncthreads();

    // ---- P0: w = exp(s-RM) + fine w-space histogram ----
    const float* qrow = qh + (bhN + n0) * D_;
    for (int i = 0; i < 4; ++i) {
        int j = tid + (i << 10);
        if (j < N_) {
            const float4* kp = (const float4*)(kh + (bhN + j) * D_);
            float4 k4[8];
#pragma unroll
            for (int q = 0; q < 8; ++q) k4[q] = kp[q];
#pragma unroll
            for (int r = 0; r < ROWS; ++r) {
                const float4* qp = (const float4*)(qrow + r * D_);
                float s = 0.f;
#pragma unroll
                for (int q = 0; q < 8; ++q) {
                    float4 q4 = qp[q];
                    s += q4.x * k4[q].x + q4.y * k4[q].y + q4.z * k4[q].z + q4.w * k4[q].w;
                }
                float w = __expf(s - RM);
                S[r * SROW + j] = w;
                int bin = (int)(__float_as_uint(w) >> 16) - WBASE;
                bin = max(0, min(bin, NBIN - 1));
                atomicAdd(&hist[(r << 9) + (bin >> 1)], 1u << ((bin & 1) << 4));
            }
        }
    }
    __syncthreads();

    // ---- histogram search (wave w -> problem w, w<8): 16 bins per lane ----
    if (wid < PROBS) {
        int prob = wid;
        int r = prob >> 1;
        int k = (prob & 1) ? K2CNT : K1CNT;
        const unsigned* hrow = hist + (r << 9) + (lane << 3);
        uint4 ha = *(const uint4*)(hrow + 0);
        uint4 hb = *(const uint4*)(hrow + 4);
        unsigned hh[8] = { ha.x, ha.y, ha.z, ha.w, hb.x, hb.y, hb.z, hb.w };
        unsigned usum = 0;
#pragma unroll
        for (int t = 0; t < 8; ++t) usum += hh[t];
        int ltot = (int)((usum & 0xFFFFu) + (usum >> 16));   // row total <= 3136: no carry
        int s = ltot;
#pragma unroll
        for (int d = 1; d < 64; d <<= 1) {
            int o = __shfl_down(s, d, 64);
            if (lane + d < 64) s += o;
        }
        int after = s - ltot;            // counts in higher lanes' (larger) bins
        if (after < k && after + ltot >= k) {   // crossing lane (unique)
            int g = after, b0 = -1, selr = 0;
#pragma unroll
            for (int m = 15; m >= 0; --m) {
                unsigned w = hh[m >> 1];
                int cm = (m & 1) ? (int)(w >> 16) : (int)(w & 0xFFFFu);
                g += cm;
                if (b0 < 0 && g >= k) { b0 = (lane << 4) + m; selr = k - (g - cm); }
            }
            M->thrBin[prob] = (unsigned)b0;
            M->selrM[prob] = selr;
        }
    }
    __syncthreads();

    // ---- P1: gather candidates + definite exp-sums (row-per-wave-group) ----
    {
        int row = wid >> 2;
        int sub = ((wid & 3) << 6) | lane;      // 0..255 within row group
        unsigned lo1 = (unsigned)(WBASE + M->thrBin[2 * row]) << 16, hi1 = lo1 + 0x10000u;
        unsigned lo2 = (unsigned)(WBASE + M->thrBin[2 * row + 1]) << 16, hi2 = lo2 + 0x10000u;
        int p1 = 2 * row, p2 = 2 * row + 1;
        float ds1 = 0.f, ds2 = 0.f;
        const float* Srow = S + row * SROW;
#pragma unroll
        for (int i = 0; i < 4; ++i) {
            int q = sub + (i << 8);
            if (q < 784) {                       // 784 quads * 4 = 3136
                float4 sv = *(const float4*)&Srow[q << 2];
                float sa[4] = { sv.x, sv.y, sv.z, sv.w };
#pragma unroll
                for (int t = 0; t < 4; ++t) {
                    unsigned u = __float_as_uint(sa[t]);
                    if (u >= hi1) {
                        ds1 += sa[t];
                        if (u >= hi2) ds2 += sa[t];
                    } else if (u >= lo1) {
                        unsigned ix = atomicAdd(&M->cntM[p1], 1u);
                        if (ix < CAP) cand[p1 * CAP + ix] = u;
                    }
                    if (u >= lo2 && u < hi2) {
                        unsigned ix = atomicAdd(&M->cntM[p2], 1u);
                        if (ix < CAP) cand[p2 * CAP + ix] = u;
                    }
                }
            }
        }
        ds1 = redsum64(ds1);
        ds2 = redsum64(ds2);
        if (lane == 0) { M->wred[wid * 2] = ds1; M->wred[wid * 2 + 1] = ds2; }
    }
    __syncthreads();

    // ---- refine (16-bit ballot-radix) + boundary sums + coef ----
    if (wid < PROBS) {
        int prob = wid;
        int cnt = (int)M->cntM[prob]; if (cnt > CAP) cnt = CAP;
        unsigned kk = (unsigned)M->selrM[prob];
        unsigned lo = (unsigned)(WBASE + M->thrBin[prob]) << 16;
        const unsigned* cp = cand + prob * CAP;
        unsigned bits = 0;
        float bsum = 0.f;
        if (cnt <= 64)       REFINE_BSUM(1)
        else if (cnt <= 128) REFINE_BSUM(2)
        else                 REFINE_BSUM(4)
        bsum = redsum64(bsum);
        if (lane == 0) {
            M->thrU[prob] = lo | bits;
            int rw = (prob >> 1) << 2;           // first wave of this row's group
            float denom = bsum
                + M->wred[(rw + 0) * 2 + (prob & 1)]
                + M->wred[(rw + 1) * 2 + (prob & 1)]
                + M->wred[(rw + 2) * 2 + (prob & 1)]
                + M->wred[(rw + 3) * 2 + (prob & 1)];
            M->coef[prob] = M->pp[prob & 1] / denom;
        }
    }
    __syncthreads();

    // ---- transform: w -> final AV coefficient (no exp, no ordf) ----
    {
        int row = wid >> 2;
        int sub = ((wid & 3) << 6) | lane;
        unsigned u1 = M->thrU[2 * row], u2 = M->thrU[2 * row + 1];
        float c1 = M->coef[2 * row];
        float c12 = c1 + M->coef[2 * row + 1];
        float* Srow = S + row * SROW;
#pragma unroll
        for (int i = 0; i < 4; ++i) {
            int q = sub + (i << 8);
            if (q < 784) {
                float4 sv = *(const float4*)&Srow[q << 2];
                float sa[4] = { sv.x, sv.y, sv.z, sv.w };
#pragma unroll
                for (int t = 0; t < 4; ++t) {
                    unsigned u = __float_as_uint(sa[t]);
                    float sel = (u >= u2) ? c12 : c1;
                    sa[t] = (u >= u1) ? sa[t] * sel : 0.f;
                }
                *(float4*)&Srow[q << 2] = make_float4(sa[0], sa[1], sa[2], sa[3]);
            }
        }
    }
    __syncthreads();

    // ---- AV: 32-j groups, V direct from global (L2-resident), reg accumulate ----
    int jj4 = lane >> 3, dq = lane & 7;
    float4 acc[ROWS];
#pragma unroll
    for (int r = 0; r < ROWS; ++r) acc[r] = make_float4(0.f, 0.f, 0.f, 0.f);
    const float* vbase = vh + bhN * D_ + (dq << 2);
    for (int g = wid; g < 98; g += 16) {        // 98 groups of 32 j
        int jb = (g << 5) + (jj4 << 2);
        float4 v0 = *(const float4*)(vbase + (size_t)(jb + 0) * D_);
        float4 v1 = *(const float4*)(vbase + (size_t)(jb + 1) * D_);
        float4 v2 = *(const float4*)(vbase + (size_t)(jb + 2) * D_);
        float4 v3 = *(const float4*)(vbase + (size_t)(jb + 3) * D_);
#pragma unroll
        for (int r = 0; r < ROWS; ++r) {
            float4 s4 = *(const float4*)&S[r * SROW + jb];
            acc[r].x += s4.x * v0.x + s4.y * v1.x + s4.z * v2.x + s4.w * v3.x;
            acc[r].y += s4.x * v0.y + s4.y * v1.y + s4.z * v2.y + s4.w * v3.y;
            acc[r].z += s4.x * v0.z + s4.y * v1.z + s4.z * v2.z + s4.w * v3.z;
            acc[r].w += s4.x * v0.w + s4.y * v1.w + s4.z * v2.w + s4.w * v3.w;
        }
    }
#pragma unroll
    for (int r = 0; r < ROWS; ++r) {
        acc[r].x = avred(acc[r].x);
        acc[r].y = avred(acc[r].y);
        acc[r].z = avred(acc[r].z);
        acc[r].w = avred(acc[r].w);
    }
    if (lane < 8) {
#pragma unroll
        for (int r = 0; r < ROWS; ++r)
            *(float4*)&red[(wid << 7) + (r << 5) + (lane << 2)] = acc[r];
    }
    __syncthreads();
    if (tid < 32 * ROWS) {
        float o = 0.f;
#pragma unroll
        for (int w = 0; w < 16; ++w) o += red[(w << 7) + tid];
        int r = tid >> 5, d = tid & 31;
        int b = bh >> 3, h = bh & 7;
        aoT[((size_t)(b * C_ + h * 32 + d)) * N_ + n0 + r] = o;
    }
}

static const int ATTN_SMEM = 50240 + 8192 + (int)sizeof(AttnMisc);

extern "C" void kernel_launch(void* const* d_in, const int* in_sizes, int n_in,
                              void* d_out, int out_size, void* d_ws, size_t ws_size,
                              hipStream_t stream)
{
    (void)in_sizes; (void)n_in; (void)out_size; (void)ws_size;
    const float* x    = (const float*)d_in[0];
    const float* y    = (const float*)d_in[1];
    const float* q_w  = (const float*)d_in[2];
    const float* q_b  = (const float*)d_in[3];
    const float* kv_w = (const float*)d_in[4];
    const float* kv_b = (const float*)d_in[5];
    const float* p_w  = (const float*)d_in[6];
    const float* p_b  = (const float*)d_in[7];
    const float* lnw  = (const float*)d_in[8];
    const float* lnb  = (const float*)d_in[9];
    const float* a1p  = (const float*)d_in[10];
    const float* a2p  = (const float*)d_in[11];
    float* out = (float*)d_out;

    float* ws = (float*)d_ws;
    const size_t PLANE = (size_t)B_ * C_ * N_;
    float* yp  = ws;
    float* yfT = ws + PLANE;
    float* qh_ = ws + 2 * PLANE;
    float* kh_ = ws + 3 * PLANE;
    float* vh_ = ws + 4 * PLANE;
    float* aoT = ws + 5 * PLANE;

    pool_kernel<<<dim3((unsigned)(PLANE / 256)), 256, 0, stream>>>(y, yp);
    ln_kernel<<<dim3(B_ * N_), 256, 0, stream>>>(yp, lnw, lnb, yfT);
    gemm_qkv<<<dim3(98, 4), 256, 0, stream>>>(x, q_w, q_b, qh_, nullptr, 0.17677669529663687f);
    gemm_qkv<<<dim3(98, 8), 256, 0, stream>>>(yfT, kv_w, kv_b, kh_, vh_, 1.0f);
    hipFuncSetAttribute(reinterpret_cast<const void*>(attn_kernel),
                        hipFuncAttributeMaxDynamicSharedMemorySize, ATTN_SMEM);
    attn_kernel<<<dim3(N_ / ROWS, B_ * NH_), 1024, ATTN_SMEM, stream>>>(qh_, kh_, vh_, a1p, a2p, aoT);
    gemm_proj<<<dim3(98, 4), 256, 0, stream>>>(aoT, p_w, p_b, out);
}